// Round 1
// 589.512 us; speedup vs baseline: 1.0365x; 1.0365x over previous
//
#include <hip/hip_runtime.h>
#include <cstdint>
#include <cstddef>

typedef __attribute__((ext_vector_type(8))) short bhalf8;   // 8 bf16 in 4 VGPRs
typedef __attribute__((ext_vector_type(4))) float f32x4;

__device__ __forceinline__ unsigned short f2bf(float f){
    unsigned int u = __float_as_uint(f);
    u += 0x7fffu + ((u >> 16) & 1u);          // round-to-nearest-even
    return (unsigned short)(u >> 16);
}

__device__ __forceinline__ float gelu_tanh(float x){
    const float c0 = 0.7978845608028654f;      // sqrt(2/pi)
    float x3 = x * x * x;
    float t = tanhf(c0 * (x + 0.044715f * x3));
    return 0.5f * x * (1.0f + t);
}

// async global->LDS, 16B per lane; LDS dest must be wave-uniform base + lane*16.
__device__ __forceinline__ void async_lds16(const unsigned short* g, unsigned short* l){
    __builtin_amdgcn_global_load_lds(
        (const __attribute__((address_space(1))) void*)g,
        (__attribute__((address_space(3))) void*)l, 16, 0, 0);
}

// ---------------------------------------------------------------------------
// Top-k(32) of 256 logits + softmax weights. 1 wave per layer.
// ---------------------------------------------------------------------------
__global__ void topk_softmax_kernel(const float* __restrict__ lg1,
                                    const float* __restrict__ lg2,
                                    int* __restrict__ idx_out,
                                    float* __restrict__ w_out)
{
    const float* lg = (blockIdx.x == 0) ? lg1 : lg2;
    int*   idxo = idx_out + blockIdx.x * 32;
    float* wo   = w_out   + blockIdx.x * 32;
    const int lane = threadIdx.x;       // 0..63
    float v[4];
    #pragma unroll
    for (int j = 0; j < 4; ++j) v[j] = lg[lane * 4 + j];
    __shared__ float svals[32];
    for (int k = 0; k < 32; ++k){
        float bv = -1e30f; int bi = 0;
        #pragma unroll
        for (int j = 0; j < 4; ++j){
            if (v[j] > bv){ bv = v[j]; bi = lane * 4 + j; }
        }
        for (int off = 32; off > 0; off >>= 1){
            float ov = __shfl_down(bv, off);
            int   oi = __shfl_down(bi, off);
            if (ov > bv){ bv = ov; bi = oi; }
        }
        bi = __shfl(bi, 0);
        if (lane == 0){ svals[k] = bv; idxo[k] = bi; }   // svals descending
        if ((bi >> 2) == lane) v[bi & 3] = -1e30f;
    }
    // parallel softmax: svals[0] is the max (selection order is descending)
    float sv = svals[lane & 31];
    float e  = expf(sv - svals[0]);
    float s  = e;
    #pragma unroll
    for (int off = 16; off > 0; off >>= 1) s += __shfl_xor(s, off);
    if (lane < 32) wo[lane] = e / s;
}

// ---------------------------------------------------------------------------
// Fused prep + all four gathers in ONE launch (block-range dispatch):
//   [0,2048)      : x fp32 -> bf16
//   [2048,4096)   : nat gather fc1_A -> Ag1  (scaled)
//   [4096,12288)  : nat gather fc2_A -> Ag2
//   [12288,14336) : tr  gather fc1_B -> Bt1
//   [14336,14848) : tr  gather fc2_B -> Bg2t (scaled)
// ---------------------------------------------------------------------------
__global__ void prep_gather_kernel(const float* __restrict__ x,  unsigned short* __restrict__ x16,
                                   const float* __restrict__ fc1A, unsigned short* __restrict__ Ag1,
                                   const float* __restrict__ fc1B, unsigned short* __restrict__ Bt1,
                                   const float* __restrict__ fc2A, unsigned short* __restrict__ Ag2,
                                   const float* __restrict__ fc2B, unsigned short* __restrict__ Bg2t,
                                   const int* __restrict__ idxb, const float* __restrict__ wb)
{
    __shared__ float tile[64][65];
    const int t = threadIdx.x;
    int b = blockIdx.x;

    if (b < 2048){                                  // ---- x -> bf16
        int v = b * 256 + t;
        float4 xx = ((const float4*)x)[v];
        ushort4 o; o.x=f2bf(xx.x); o.y=f2bf(xx.y); o.z=f2bf(xx.z); o.w=f2bf(xx.w);
        ((ushort4*)x16)[v] = o;
        return;
    }
    b -= 2048;
    if (b < 10240){                                 // ---- natural gathers
        const float* src; unsigned short* dst; const int* idx; const float* w;
        int Drows, use_scale, v;
        if (b < 2048){ src=fc1A; dst=Ag1; idx=idxb;    w=wb;    Drows=1024; use_scale=1; v=b*256+t; }
        else         { src=fc2A; dst=Ag2; idx=idxb+32; w=wb+32; Drows=4096; use_scale=0; v=(b-2048)*256+t; }
        int c4 = v & 511;          // 512 float4 per dst row (2048 cols)
        int d  = v >> 9;
        int k  = c4 >> 4;          // expert slot 0..31
        int r4 = c4 & 15;
        int p  = idx[k];
        float sc = use_scale ? w[k] : 1.0f;
        float4 xx = *((const float4*)(src + ((size_t)p * Drows + d) * 64) + r4);
        ushort4 o;
        o.x = f2bf(sc * xx.x); o.y = f2bf(sc * xx.y);
        o.z = f2bf(sc * xx.z); o.w = f2bf(sc * xx.w);
        *(ushort4*)(dst + (size_t)d * 2048 + k * 64 + r4 * 4) = o;
        return;
    }
    b -= 10240;                                     // ---- transpose gathers
    const float* src; unsigned short* dst; const int* idx; const float* w;
    int Fcols, use_scale;
    if (b < 2048){ src=fc1B; dst=Bt1;  idx=idxb;    w=wb;    Fcols=4096; use_scale=0; }
    else         { src=fc2B; dst=Bg2t; idx=idxb+32; w=wb+32; Fcols=1024; use_scale=1; b -= 2048; }
    const int k  = b & 31;
    const int f0 = (b >> 5) * 64;
    const int p  = idx[k];
    const float sc = use_scale ? w[k] : 1.0f;
    const int cf = t & 15;
    const int r0 = t >> 4;
    #pragma unroll
    for (int pass = 0; pass < 4; ++pass){
        int r = r0 + pass * 16;
        float4 xx = *((const float4*)(src + ((size_t)p * 64 + r) * Fcols + f0) + cf);
        tile[r][cf * 4 + 0] = xx.x; tile[r][cf * 4 + 1] = xx.y;
        tile[r][cf * 4 + 2] = xx.z; tile[r][cf * 4 + 3] = xx.w;
    }
    __syncthreads();
    const int r4  = t & 15;
    const int fl0 = t >> 4;
    #pragma unroll
    for (int pass = 0; pass < 4; ++pass){
        int fl = fl0 + pass * 16;
        ushort4 o;
        o.x = f2bf(sc * tile[r4 * 4 + 0][fl]);
        o.y = f2bf(sc * tile[r4 * 4 + 1][fl]);
        o.z = f2bf(sc * tile[r4 * 4 + 2][fl]);
        o.w = f2bf(sc * tile[r4 * 4 + 3][fl]);
        *(ushort4*)(dst + (size_t)(f0 + fl) * 2048 + k * 64 + r4 * 4) = o;
    }
}

// ---------------------------------------------------------------------------
// NT bf16 GEMM body: C(M,N) = A(M,K)*Bt(N,K)^T, fp32 acc, 128x128 tile.
// BK=64 as two conflict-free BK=32 stages in 4 separate 8KB LDS buffers.
// EPI: 0 bf16 store, 1 gelu+bf16 store, 2 fp32 store (split-K partial).
// ---------------------------------------------------------------------------
template<int EPI>
__device__ __forceinline__ void gemm_body(unsigned short* smem,
                                          const unsigned short* __restrict__ A,
                                          const unsigned short* __restrict__ Bt,
                                          void* __restrict__ Cout,
                                          int N, int K, int Kslice, int kbeg,
                                          int bm, int bn)
{
    unsigned short* sA0 = smem;
    unsigned short* sA1 = smem + 4096;
    unsigned short* sB0 = smem + 8192;
    unsigned short* sB1 = smem + 12288;
    const int t    = threadIdx.x;
    const int wave = t >> 6;
    const int lane = t & 63;
    const int wr   = (wave >> 1) * 64;
    const int wc   = (wave & 1) * 64;
    const int m16  = lane & 15;
    const int quad = lane >> 4;
    const int srow = t >> 2;             // 64 rows per staging pass
    const int scol = t & 3;              // 16B chunk within 64B (BK=32) row

    f32x4 acc[4][4];
    const f32x4 z = {0.f, 0.f, 0.f, 0.f};
    #pragma unroll
    for (int i = 0; i < 4; ++i)
        #pragma unroll
        for (int j = 0; j < 4; ++j) acc[i][j] = z;

    const unsigned short* Arow = A  + (size_t)(bm + srow) * K + scol * 8 + kbeg;
    const unsigned short* Brow = Bt + (size_t)(bn + srow) * K + scol * 8 + kbeg;
    const size_t rstep = (size_t)64 * K;
    unsigned short* lA0 = sA0 + t * 8;   // byte offset == t*16 in each buffer
    unsigned short* lA1 = sA1 + t * 8;
    unsigned short* lB0 = sB0 + t * 8;
    unsigned short* lB1 = sB1 + t * 8;

    for (int k0 = 0; k0 < Kslice; k0 += 64){
        async_lds16(Arow + k0,              lA0);
        async_lds16(Arow + rstep + k0,      lA0 + 64 * 32);
        async_lds16(Arow + k0 + 32,         lA1);
        async_lds16(Arow + rstep + k0 + 32, lA1 + 64 * 32);
        async_lds16(Brow + k0,              lB0);
        async_lds16(Brow + rstep + k0,      lB0 + 64 * 32);
        async_lds16(Brow + k0 + 32,         lB1);
        async_lds16(Brow + rstep + k0 + 32, lB1 + 64 * 32);
        __syncthreads();

        bhalf8 af0[4], bf0[4], af1[4], bf1[4];
        #pragma unroll
        for (int i = 0; i < 4; ++i){
            af0[i] = *(const bhalf8*)(sA0 + (wr + i * 16 + m16) * 32 + quad * 8);
            af1[i] = *(const bhalf8*)(sA1 + (wr + i * 16 + m16) * 32 + quad * 8);
        }
        #pragma unroll
        for (int j = 0; j < 4; ++j){
            bf0[j] = *(const bhalf8*)(sB0 + (wc + j * 16 + m16) * 32 + quad * 8);
            bf1[j] = *(const bhalf8*)(sB1 + (wc + j * 16 + m16) * 32 + quad * 8);
        }

        #pragma unroll
        for (int i = 0; i < 4; ++i)
            #pragma unroll
            for (int j = 0; j < 4; ++j)
                acc[i][j] = __builtin_amdgcn_mfma_f32_16x16x32_bf16(af0[i], bf0[j], acc[i][j], 0, 0, 0);
        #pragma unroll
        for (int i = 0; i < 4; ++i)
            #pragma unroll
            for (int j = 0; j < 4; ++j)
                acc[i][j] = __builtin_amdgcn_mfma_f32_16x16x32_bf16(af1[i], bf1[j], acc[i][j], 0, 0, 0);
        __syncthreads();
    }

    // Epilogue. C/D layout: col = lane&15, row = quad*4 + reg  [m89/m91]
    #pragma unroll
    for (int i = 0; i < 4; ++i){
        #pragma unroll
        for (int j = 0; j < 4; ++j){
            #pragma unroll
            for (int r = 0; r < 4; ++r){
                int row = bm + wr + i * 16 + quad * 4 + r;
                int col = bn + wc + j * 16 + m16;
                float vv = acc[i][j][r];
                if (EPI == 1) vv = gelu_tanh(vv);
                if (EPI == 2) ((float*)Cout)[(size_t)row * N + col] = vv;
                else ((unsigned short*)Cout)[(size_t)row * N + col] = f2bf(vv);
            }
        }
    }
}

// XCD-chunked bijective swizzle for 512-block grids (512 = 8 XCDs * 64).
__device__ __forceinline__ int xcd_swz512(int id){ return (id & 7) * 64 + (id >> 3); }

// GEMM1 (W1t = Bt1 * Ag1^T, 4096x1024) and GEMM3 (W2t = Bg2t * Ag2^T,
// 1024x4096) fused into one 512-block launch: both K=2048, independent.
__launch_bounds__(256, 2)
__global__ void gemm13_kernel(const unsigned short* __restrict__ A1,
                              const unsigned short* __restrict__ B1,
                              unsigned short* __restrict__ C1,
                              const unsigned short* __restrict__ A2,
                              const unsigned short* __restrict__ B2,
                              unsigned short* __restrict__ C2)
{
    __shared__ unsigned short smem[4 * 128 * 32];
    int id = xcd_swz512(blockIdx.x);
    if (id < 256){
        gemm_body<0>(smem, A1, B1, C1, 1024, 2048, 2048, 0,
                     (id >> 3) * 128, (id & 7) * 128);
    } else {
        id -= 256;
        gemm_body<0>(smem, A2, B2, C2, 4096, 2048, 2048, 0,
                     (id >> 5) * 128, (id & 31) * 128);
    }
}

// GEMM2: h(2048x4096) = gelu( x16 * W1t^T ), K=1024
__launch_bounds__(256, 2)
__global__ void gemm2_kernel(const unsigned short* __restrict__ A,
                             const unsigned short* __restrict__ Bt,
                             unsigned short* __restrict__ C)
{
    __shared__ unsigned short smem[4 * 128 * 32];
    int id = xcd_swz512(blockIdx.x);
    gemm_body<1>(smem, A, Bt, C, 4096, 1024, 1024, 0,
                 (id >> 5) * 128, (id & 31) * 128);
}

// GEMM4: out(2048x1024) = hbuf * W2t^T, split-K=4 -> fp32 partial buffers
__launch_bounds__(256, 2)
__global__ void gemm4_kernel(const unsigned short* __restrict__ A,
                             const unsigned short* __restrict__ Bt,
                             float* __restrict__ part)
{
    __shared__ unsigned short smem[4 * 128 * 32];
    int id = xcd_swz512(blockIdx.x);
    int bz = id >> 7;                  // slice 0..3
    int r  = id & 127;
    float* Cs = part + (size_t)bz * (2048 * 1024);
    gemm_body<2>(smem, A, Bt, Cs, 1024, 4096, 1024, bz * 1024,
                 (r >> 3) * 128, (r & 7) * 128);
}

// Sum the 4 split-K partial buffers into the fp32 output.
__global__ void reduce4_kernel(const float4* __restrict__ p, float4* __restrict__ out)
{
    const int S = 524288;              // float4 per slice (2048*1024 fp32)
    int v = blockIdx.x * 256 + threadIdx.x;
    float4 a = p[v], b = p[v + S], c = p[v + 2 * S], d = p[v + 3 * S];
    float4 r;
    r.x = (a.x + b.x) + (c.x + d.x);
    r.y = (a.y + b.y) + (c.y + d.y);
    r.z = (a.z + b.z) + (c.z + d.z);
    r.w = (a.w + b.w) + (c.w + d.w);
    out[v] = r;
}

// ---------------------------------------------------------------------------
extern "C" void kernel_launch(void* const* d_in, const int* in_sizes, int n_in,
                              void* d_out, int out_size, void* d_ws, size_t ws_size,
                              hipStream_t stream)
{
    const float* x    = (const float*)d_in[0];   // (2,1024,1024)
    const float* fc1A = (const float*)d_in[1];   // (256,1024,64)
    const float* fc1B = (const float*)d_in[2];   // (256,64,4096)
    const float* fc2A = (const float*)d_in[3];   // (256,4096,64)
    const float* fc2B = (const float*)d_in[4];   // (256,64,1024)
    const float* lg1  = (const float*)d_in[5];   // (256,)
    const float* lg2  = (const float*)d_in[6];   // (256,)
    float* out = (float*)d_out;                  // (2,1024,1024) fp32

    char* ws = (char*)d_ws;
    int*            idxb = (int*)(ws + 0);
    float*          wb   = (float*)(ws + 256);
    char* base = ws + 4096;
    unsigned short* x16  = (unsigned short*)(base);                  // 4 MB  (2048x1024)
    unsigned short* Ag1  = (unsigned short*)(base + (4ull  << 20));  // 4 MB  (1024x2048)
    unsigned short* Bt1  = (unsigned short*)(base + (8ull  << 20));  // 16 MB (4096x2048)
    unsigned short* Ag2  = (unsigned short*)(base + (24ull << 20));  // 16 MB (4096x2048)
    unsigned short* Bg2t = (unsigned short*)(base + (40ull << 20));  // 4 MB  (1024x2048)
    unsigned short* W1t  = (unsigned short*)(base + (44ull << 20));  // 8 MB  (4096x1024)
    unsigned short* W2t  = (unsigned short*)(base + (52ull << 20));  // 8 MB  (1024x4096)
    unsigned short* hbuf = (unsigned short*)(base + (60ull << 20));  // 16 MB (2048x4096)
    float*          part = (float*)(base + (76ull << 20));           // 32 MB (4 x 2048x1024 fp32)

    // 1. top-k + softmax (both layers)
    topk_softmax_kernel<<<dim3(2), dim3(64), 0, stream>>>(lg1, lg2, idxb, wb);

    // 2. fused: x->bf16 + all four gathers (one launch)
    prep_gather_kernel<<<dim3(14848), dim3(256), 0, stream>>>(
        x, x16, fc1A, Ag1, fc1B, Bt1, fc2A, Ag2, fc2B, Bg2t, idxb, wb);

    // 3. GEMM1+GEMM3 fused (512 blocks, 2/CU, XCD-swizzled)
    gemm13_kernel<<<dim3(512), dim3(256), 0, stream>>>(Bt1, Ag1, W1t, Bg2t, Ag2, W2t);

    // 4. GEMM2: h = gelu( x16 * W1t^T )
    gemm2_kernel<<<dim3(512), dim3(256), 0, stream>>>(x16, W1t, hbuf);

    // 5. GEMM4: split-K=4 fp32 partials (no atomics)
    gemm4_kernel<<<dim3(512), dim3(256), 0, stream>>>(hbuf, W2t, part);

    // 6. reduce partials -> out
    reduce4_kernel<<<dim3(2048), dim3(256), 0, stream>>>((const float4*)part, (float4*)out);
}

// Round 2
// 578.822 us; speedup vs baseline: 1.0557x; 1.0185x over previous
//
#include <hip/hip_runtime.h>
#include <cstdint>
#include <cstddef>

typedef __attribute__((ext_vector_type(8))) short bhalf8;   // 8 bf16 in 4 VGPRs
typedef __attribute__((ext_vector_type(4))) float f32x4;

__device__ __forceinline__ unsigned short f2bf(float f){
    unsigned int u = __float_as_uint(f);
    u += 0x7fffu + ((u >> 16) & 1u);          // round-to-nearest-even
    return (unsigned short)(u >> 16);
}

// gelu(x) = 0.5x(1+tanh(c0(x+0.044715x^3))) = x - x/(e+1), e = exp(2*c0*(...))
__device__ __forceinline__ float gelu_tanh(float x){
    const float c1 = 2.302584f;                // 2*log2(e)*sqrt(2/pi)
    float y  = x + 0.044715f * x * x * x;
    float e  = __builtin_amdgcn_exp2f(c1 * y); // e^(2*c0*y); inf/0 at extremes ok
    float r  = __builtin_amdgcn_rcpf(e + 1.0f);
    return x - x * r;                          // e=inf -> x; e=0 -> 0
}

// async global->LDS, 16B per lane; LDS dest must be wave-uniform base + lane*16.
__device__ __forceinline__ void async_lds16(const unsigned short* g, unsigned short* l){
    __builtin_amdgcn_global_load_lds(
        (const __attribute__((address_space(1))) void*)g,
        (__attribute__((address_space(3))) void*)l, 16, 0, 0);
}

// ---------------------------------------------------------------------------
// Top-k(32) of 256 logits + softmax weights. 1 wave per layer.
// ---------------------------------------------------------------------------
__global__ void topk_softmax_kernel(const float* __restrict__ lg1,
                                    const float* __restrict__ lg2,
                                    int* __restrict__ idx_out,
                                    float* __restrict__ w_out)
{
    const float* lg = (blockIdx.x == 0) ? lg1 : lg2;
    int*   idxo = idx_out + blockIdx.x * 32;
    float* wo   = w_out   + blockIdx.x * 32;
    const int lane = threadIdx.x;       // 0..63
    float v[4];
    #pragma unroll
    for (int j = 0; j < 4; ++j) v[j] = lg[lane * 4 + j];
    __shared__ float svals[32];
    for (int k = 0; k < 32; ++k){
        float bv = -1e30f; int bi = 0;
        #pragma unroll
        for (int j = 0; j < 4; ++j){
            if (v[j] > bv){ bv = v[j]; bi = lane * 4 + j; }
        }
        for (int off = 32; off > 0; off >>= 1){
            float ov = __shfl_down(bv, off);
            int   oi = __shfl_down(bi, off);
            if (ov > bv){ bv = ov; bi = oi; }
        }
        bi = __shfl(bi, 0);
        if (lane == 0){ svals[k] = bv; idxo[k] = bi; }   // svals descending
        if ((bi >> 2) == lane) v[bi & 3] = -1e30f;
    }
    // parallel softmax: svals[0] is the max (selection order is descending)
    float sv = svals[lane & 31];
    float e  = expf(sv - svals[0]);
    float s  = e;
    #pragma unroll
    for (int off = 16; off > 0; off >>= 1) s += __shfl_xor(s, off);
    if (lane < 32) wo[lane] = e / s;
}

// ---------------------------------------------------------------------------
// Fused prep + all four gathers in ONE launch (block-range dispatch):
//   [0,2048)      : x fp32 -> bf16
//   [2048,4096)   : nat gather fc1_A -> Ag1  (scaled)
//   [4096,12288)  : nat gather fc2_A -> Ag2
//   [12288,14336) : tr  gather fc1_B -> Bt1
//   [14336,14848) : tr  gather fc2_B -> Bg2t (scaled)
// ---------------------------------------------------------------------------
__global__ void prep_gather_kernel(const float* __restrict__ x,  unsigned short* __restrict__ x16,
                                   const float* __restrict__ fc1A, unsigned short* __restrict__ Ag1,
                                   const float* __restrict__ fc1B, unsigned short* __restrict__ Bt1,
                                   const float* __restrict__ fc2A, unsigned short* __restrict__ Ag2,
                                   const float* __restrict__ fc2B, unsigned short* __restrict__ Bg2t,
                                   const int* __restrict__ idxb, const float* __restrict__ wb)
{
    __shared__ float tile[64][65];
    const int t = threadIdx.x;
    int b = blockIdx.x;

    if (b < 2048){                                  // ---- x -> bf16
        int v = b * 256 + t;
        float4 xx = ((const float4*)x)[v];
        ushort4 o; o.x=f2bf(xx.x); o.y=f2bf(xx.y); o.z=f2bf(xx.z); o.w=f2bf(xx.w);
        ((ushort4*)x16)[v] = o;
        return;
    }
    b -= 2048;
    if (b < 10240){                                 // ---- natural gathers
        const float* src; unsigned short* dst; const int* idx; const float* w;
        int Drows, use_scale, v;
        if (b < 2048){ src=fc1A; dst=Ag1; idx=idxb;    w=wb;    Drows=1024; use_scale=1; v=b*256+t; }
        else         { src=fc2A; dst=Ag2; idx=idxb+32; w=wb+32; Drows=4096; use_scale=0; v=(b-2048)*256+t; }
        int c4 = v & 511;          // 512 float4 per dst row (2048 cols)
        int d  = v >> 9;
        int k  = c4 >> 4;          // expert slot 0..31
        int r4 = c4 & 15;
        int p  = idx[k];
        float sc = use_scale ? w[k] : 1.0f;
        float4 xx = *((const float4*)(src + ((size_t)p * Drows + d) * 64) + r4);
        ushort4 o;
        o.x = f2bf(sc * xx.x); o.y = f2bf(sc * xx.y);
        o.z = f2bf(sc * xx.z); o.w = f2bf(sc * xx.w);
        *(ushort4*)(dst + (size_t)d * 2048 + k * 64 + r4 * 4) = o;
        return;
    }
    b -= 10240;                                     // ---- transpose gathers
    const float* src; unsigned short* dst; const int* idx; const float* w;
    int Fcols, use_scale;
    if (b < 2048){ src=fc1B; dst=Bt1;  idx=idxb;    w=wb;    Fcols=4096; use_scale=0; }
    else         { src=fc2B; dst=Bg2t; idx=idxb+32; w=wb+32; Fcols=1024; use_scale=1; b -= 2048; }
    const int k  = b & 31;
    const int f0 = (b >> 5) * 64;
    const int p  = idx[k];
    const float sc = use_scale ? w[k] : 1.0f;
    const int cf = t & 15;
    const int r0 = t >> 4;
    #pragma unroll
    for (int pass = 0; pass < 4; ++pass){
        int r = r0 + pass * 16;
        float4 xx = *((const float4*)(src + ((size_t)p * 64 + r) * Fcols + f0) + cf);
        tile[r][cf * 4 + 0] = xx.x; tile[r][cf * 4 + 1] = xx.y;
        tile[r][cf * 4 + 2] = xx.z; tile[r][cf * 4 + 3] = xx.w;
    }
    __syncthreads();
    const int r4  = t & 15;
    const int fl0 = t >> 4;
    #pragma unroll
    for (int pass = 0; pass < 4; ++pass){
        int fl = fl0 + pass * 16;
        ushort4 o;
        o.x = f2bf(sc * tile[r4 * 4 + 0][fl]);
        o.y = f2bf(sc * tile[r4 * 4 + 1][fl]);
        o.z = f2bf(sc * tile[r4 * 4 + 2][fl]);
        o.w = f2bf(sc * tile[r4 * 4 + 3][fl]);
        *(ushort4*)(dst + (size_t)(f0 + fl) * 2048 + k * 64 + r4 * 4) = o;
    }
}

// ---------------------------------------------------------------------------
// NT bf16 GEMM body: C(M,N) = A(M,K)*Bt(N,K)^T, fp32 acc, 128x128 tile.
// 2-phase double-buffered pipeline (T3-minimum): 2 LDS slots x 32KB, next
// K-tile's 8 global_load_lds issued BEFORE current tile's ds_read+MFMA, one
// counted-drain (vmcnt0+lgkmcnt0) + raw s_barrier per K-step. Loads hide
// under the 32-MFMA compute phase instead of being serially exposed.
// Per-slot layout (shorts): A0=0 A1=4096 B0=8192 B1=12288, halves at +2048.
// EPI: 0 bf16 store, 1 gelu+bf16 store, 2 fp32 store (split-K partial).
// ---------------------------------------------------------------------------
template<int EPI>
__device__ __forceinline__ void gemm_body(unsigned short* smem,
                                          const unsigned short* __restrict__ A,
                                          const unsigned short* __restrict__ Bt,
                                          void* __restrict__ Cout,
                                          int N, int K, int Kslice, int kbeg,
                                          int bm, int bn)
{
    const int t    = threadIdx.x;
    const int wave = t >> 6;
    const int lane = t & 63;
    const int wr   = (wave >> 1) * 64;
    const int wc   = (wave & 1) * 64;
    const int m16  = lane & 15;
    const int quad = lane >> 4;
    const int srow = t >> 2;             // 64 rows per staging pass
    const int scol = t & 3;              // 16B chunk within 64B (BK=32) row

    f32x4 acc[4][4];
    const f32x4 z = {0.f, 0.f, 0.f, 0.f};
    #pragma unroll
    for (int i = 0; i < 4; ++i)
        #pragma unroll
        for (int j = 0; j < 4; ++j) acc[i][j] = z;

    const unsigned short* Arow = A  + (size_t)(bm + srow) * K + scol * 8 + kbeg;
    const unsigned short* Brow = Bt + (size_t)(bn + srow) * K + scol * 8 + kbeg;
    const size_t rstep = (size_t)64 * K;

    auto stage = [&](int slot, int k0){
        unsigned short* s = smem + slot * 16384 + t * 8;
        async_lds16(Arow + k0,              s);
        async_lds16(Arow + rstep + k0,      s + 2048);
        async_lds16(Arow + k0 + 32,         s + 4096);
        async_lds16(Arow + rstep + k0 + 32, s + 6144);
        async_lds16(Brow + k0,              s + 8192);
        async_lds16(Brow + rstep + k0,      s + 10240);
        async_lds16(Brow + k0 + 32,         s + 12288);
        async_lds16(Brow + rstep + k0 + 32, s + 14336);
    };

    const int nIter = Kslice >> 6;

    // prologue: tile 0 into slot 0
    stage(0, 0);
    asm volatile("s_waitcnt vmcnt(0)" ::: "memory");
    __builtin_amdgcn_s_barrier();

    for (int it = 0; it < nIter; ++it){
        unsigned short* sb = smem + (it & 1) * 16384;
        if (it + 1 < nIter) stage((it + 1) & 1, (it + 1) * 64);  // prefetch

        bhalf8 af0[4], bf0[4], af1[4], bf1[4];
        #pragma unroll
        for (int i = 0; i < 4; ++i){
            af0[i] = *(const bhalf8*)(sb +         (wr + i * 16 + m16) * 32 + quad * 8);
            af1[i] = *(const bhalf8*)(sb + 4096  + (wr + i * 16 + m16) * 32 + quad * 8);
        }
        #pragma unroll
        for (int j = 0; j < 4; ++j){
            bf0[j] = *(const bhalf8*)(sb + 8192  + (wc + j * 16 + m16) * 32 + quad * 8);
            bf1[j] = *(const bhalf8*)(sb + 12288 + (wc + j * 16 + m16) * 32 + quad * 8);
        }

        #pragma unroll
        for (int i = 0; i < 4; ++i)
            #pragma unroll
            for (int j = 0; j < 4; ++j)
                acc[i][j] = __builtin_amdgcn_mfma_f32_16x16x32_bf16(af0[i], bf0[j], acc[i][j], 0, 0, 0);
        #pragma unroll
        for (int i = 0; i < 4; ++i)
            #pragma unroll
            for (int j = 0; j < 4; ++j)
                acc[i][j] = __builtin_amdgcn_mfma_f32_16x16x32_bf16(af1[i], bf1[j], acc[i][j], 0, 0, 0);

        if (it + 1 < nIter){
            // prefetched tile landed (it had the whole compute phase in
            // flight); all this tile's ds_reads serviced -> safe to overwrite
            // the other slot next iteration.
            asm volatile("s_waitcnt vmcnt(0) lgkmcnt(0)" ::: "memory");
            __builtin_amdgcn_s_barrier();
        }
    }

    // Epilogue. C/D layout: col = lane&15, row = quad*4 + reg  [m89/m91]
    #pragma unroll
    for (int i = 0; i < 4; ++i){
        #pragma unroll
        for (int j = 0; j < 4; ++j){
            #pragma unroll
            for (int r = 0; r < 4; ++r){
                int row = bm + wr + i * 16 + quad * 4 + r;
                int col = bn + wc + j * 16 + m16;
                float vv = acc[i][j][r];
                if (EPI == 1) vv = gelu_tanh(vv);
                if (EPI == 2) ((float*)Cout)[(size_t)row * N + col] = vv;
                else ((unsigned short*)Cout)[(size_t)row * N + col] = f2bf(vv);
            }
        }
    }
}

// XCD-chunked bijective swizzle for 512-block grids (512 = 8 XCDs * 64).
__device__ __forceinline__ int xcd_swz512(int id){ return (id & 7) * 64 + (id >> 3); }

// GEMM1 (W1t = Bt1 * Ag1^T, 4096x1024) and GEMM3 (W2t = Bg2t * Ag2^T,
// 1024x4096) fused into one 512-block launch: both K=2048, independent.
__launch_bounds__(256, 2)
__global__ void gemm13_kernel(const unsigned short* __restrict__ A1,
                              const unsigned short* __restrict__ B1,
                              unsigned short* __restrict__ C1,
                              const unsigned short* __restrict__ A2,
                              const unsigned short* __restrict__ B2,
                              unsigned short* __restrict__ C2)
{
    __shared__ unsigned short smem[2 * 16384];   // 64 KB, 2 pipeline slots
    int id = xcd_swz512(blockIdx.x);
    if (id < 256){
        gemm_body<0>(smem, A1, B1, C1, 1024, 2048, 2048, 0,
                     (id >> 3) * 128, (id & 7) * 128);
    } else {
        id -= 256;
        gemm_body<0>(smem, A2, B2, C2, 4096, 2048, 2048, 0,
                     (id >> 5) * 128, (id & 31) * 128);
    }
}

// GEMM2: h(2048x4096) = gelu( x16 * W1t^T ), K=1024
__launch_bounds__(256, 2)
__global__ void gemm2_kernel(const unsigned short* __restrict__ A,
                             const unsigned short* __restrict__ Bt,
                             unsigned short* __restrict__ C)
{
    __shared__ unsigned short smem[2 * 16384];
    int id = xcd_swz512(blockIdx.x);
    gemm_body<1>(smem, A, Bt, C, 4096, 1024, 1024, 0,
                 (id >> 5) * 128, (id & 31) * 128);
}

// GEMM4: out(2048x1024) = hbuf * W2t^T, split-K=4 -> fp32 partial buffers
__launch_bounds__(256, 2)
__global__ void gemm4_kernel(const unsigned short* __restrict__ A,
                             const unsigned short* __restrict__ Bt,
                             float* __restrict__ part)
{
    __shared__ unsigned short smem[2 * 16384];
    int id = xcd_swz512(blockIdx.x);
    int bz = id >> 7;                  // slice 0..3
    int r  = id & 127;
    float* Cs = part + (size_t)bz * (2048 * 1024);
    gemm_body<2>(smem, A, Bt, Cs, 1024, 4096, 1024, bz * 1024,
                 (r >> 3) * 128, (r & 7) * 128);
}

// Sum the 4 split-K partial buffers into the fp32 output.
__global__ void reduce4_kernel(const float4* __restrict__ p, float4* __restrict__ out)
{
    const int S = 524288;              // float4 per slice (2048*1024 fp32)
    int v = blockIdx.x * 256 + threadIdx.x;
    float4 a = p[v], b = p[v + S], c = p[v + 2 * S], d = p[v + 3 * S];
    float4 r;
    r.x = (a.x + b.x) + (c.x + d.x);
    r.y = (a.y + b.y) + (c.y + d.y);
    r.z = (a.z + b.z) + (c.z + d.z);
    r.w = (a.w + b.w) + (c.w + d.w);
    out[v] = r;
}

// ---------------------------------------------------------------------------
extern "C" void kernel_launch(void* const* d_in, const int* in_sizes, int n_in,
                              void* d_out, int out_size, void* d_ws, size_t ws_size,
                              hipStream_t stream)
{
    const float* x    = (const float*)d_in[0];   // (2,1024,1024)
    const float* fc1A = (const float*)d_in[1];   // (256,1024,64)
    const float* fc1B = (const float*)d_in[2];   // (256,64,4096)
    const float* fc2A = (const float*)d_in[3];   // (256,4096,64)
    const float* fc2B = (const float*)d_in[4];   // (256,64,1024)
    const float* lg1  = (const float*)d_in[5];   // (256,)
    const float* lg2  = (const float*)d_in[6];   // (256,)
    float* out = (float*)d_out;                  // (2,1024,1024) fp32

    char* ws = (char*)d_ws;
    int*            idxb = (int*)(ws + 0);
    float*          wb   = (float*)(ws + 256);
    char* base = ws + 4096;
    unsigned short* x16  = (unsigned short*)(base);                  // 4 MB  (2048x1024)
    unsigned short* Ag1  = (unsigned short*)(base + (4ull  << 20));  // 4 MB  (1024x2048)
    unsigned short* Bt1  = (unsigned short*)(base + (8ull  << 20));  // 16 MB (4096x2048)
    unsigned short* Ag2  = (unsigned short*)(base + (24ull << 20));  // 16 MB (4096x2048)
    unsigned short* Bg2t = (unsigned short*)(base + (40ull << 20));  // 4 MB  (1024x2048)
    unsigned short* W1t  = (unsigned short*)(base + (44ull << 20));  // 8 MB  (4096x1024)
    unsigned short* W2t  = (unsigned short*)(base + (52ull << 20));  // 8 MB  (1024x4096)
    unsigned short* hbuf = (unsigned short*)(base + (60ull << 20));  // 16 MB (2048x4096)
    float*          part = (float*)(base + (76ull << 20));           // 32 MB (4 x 2048x1024 fp32)

    // 1. top-k + softmax (both layers)
    topk_softmax_kernel<<<dim3(2), dim3(64), 0, stream>>>(lg1, lg2, idxb, wb);

    // 2. fused: x->bf16 + all four gathers (one launch)
    prep_gather_kernel<<<dim3(14848), dim3(256), 0, stream>>>(
        x, x16, fc1A, Ag1, fc1B, Bt1, fc2A, Ag2, fc2B, Bg2t, idxb, wb);

    // 3. GEMM1+GEMM3 fused (512 blocks, 2/CU, XCD-swizzled)
    gemm13_kernel<<<dim3(512), dim3(256), 0, stream>>>(Bt1, Ag1, W1t, Bg2t, Ag2, W2t);

    // 4. GEMM2: h = gelu( x16 * W1t^T )
    gemm2_kernel<<<dim3(512), dim3(256), 0, stream>>>(x16, W1t, hbuf);

    // 5. GEMM4: split-K=4 fp32 partials (no atomics)
    gemm4_kernel<<<dim3(512), dim3(256), 0, stream>>>(hbuf, W2t, part);

    // 6. reduce partials -> out
    reduce4_kernel<<<dim3(2048), dim3(256), 0, stream>>>((const float4*)part, (float4*)out);
}